// Round 6
// baseline (610.517 us; speedup 1.0000x reference)
//
#include <hip/hip_runtime.h>
#include <hip/hip_bf16.h>

#define IN_CH 128
#define HID   16
#define N1_T  100000
#define N2_T  10000
#define OUT_CH 64

// ---------------------------------------------------------------------------
// Kernel 1 (v3): xp = x @ W1   (500000x128 @ 128x16).
// Each thread: 4 rows x 4 channels. W1 staged TRANSPOSED in LDS (wt[c][k])
// so one ds_read_b128 covers 4 k of one channel; W1 reads amortize over the
// 4 rows. x read straight from global as float4 (4-lane broadcast within a
// row group; lines reused across k via L1). No compiler-scalarization
// reliance anywhere. Per-CU budget: HBM 50 cyc/row > LDS 24 > VALU 16.
// ---------------------------------------------------------------------------
constexpr int WT_STRIDE = 132;  // floats; %4==0 keeps b128 alignment

__global__ __launch_bounds__(256) void proj_kernel(
    const float* __restrict__ x, const float* __restrict__ W1,
    float* __restrict__ xp, int n0) {
  __shared__ float wt[HID * WT_STRIDE];  // 8.4 KB

  const int tid = threadIdx.x;

  // stage W1 transposed: thread k<128 loads W1[k][0..15], scatters wt[c][k]
  if (tid < IN_CH) {
    const float4* wrow = reinterpret_cast<const float4*>(W1 + tid * HID);
    float4 w0 = wrow[0], w1 = wrow[1], w2 = wrow[2], w3 = wrow[3];
    wt[ 0 * WT_STRIDE + tid] = w0.x; wt[ 1 * WT_STRIDE + tid] = w0.y;
    wt[ 2 * WT_STRIDE + tid] = w0.z; wt[ 3 * WT_STRIDE + tid] = w0.w;
    wt[ 4 * WT_STRIDE + tid] = w1.x; wt[ 5 * WT_STRIDE + tid] = w1.y;
    wt[ 6 * WT_STRIDE + tid] = w1.z; wt[ 7 * WT_STRIDE + tid] = w1.w;
    wt[ 8 * WT_STRIDE + tid] = w2.x; wt[ 9 * WT_STRIDE + tid] = w2.y;
    wt[10 * WT_STRIDE + tid] = w2.z; wt[11 * WT_STRIDE + tid] = w2.w;
    wt[12 * WT_STRIDE + tid] = w3.x; wt[13 * WT_STRIDE + tid] = w3.y;
    wt[14 * WT_STRIDE + tid] = w3.z; wt[15 * WT_STRIDE + tid] = w3.w;
  }
  __syncthreads();

  // thread -> (row group g, channel quad q); 4 rows per thread
  const int q = tid & 3;          // channels 4q..4q+3
  const int g = tid >> 2;         // 64 row-groups per block
  const int r0 = blockIdx.x * 256 + g * 4;
  if (r0 >= n0) return;

  const float* wq = &wt[(q * 4) * WT_STRIDE];  // 4 channel rows, k-major
  const float* xr0 = x + (size_t)r0 * IN_CH;
  const float* xr1 = x + (size_t)min(r0 + 1, n0 - 1) * IN_CH;
  const float* xr2 = x + (size_t)min(r0 + 2, n0 - 1) * IN_CH;
  const float* xr3 = x + (size_t)min(r0 + 3, n0 - 1) * IN_CH;

  float4 acc0 = make_float4(0.f, 0.f, 0.f, 0.f);
  float4 acc1 = acc0, acc2 = acc0, acc3 = acc0;

  #pragma unroll 8
  for (int kb = 0; kb < IN_CH; kb += 4) {
    // 4 channel-slices of W1T: wt[c][kb..kb+3]
    const float4 wa = *reinterpret_cast<const float4*>(wq + 0 * WT_STRIDE + kb);
    const float4 wb = *reinterpret_cast<const float4*>(wq + 1 * WT_STRIDE + kb);
    const float4 wc = *reinterpret_cast<const float4*>(wq + 2 * WT_STRIDE + kb);
    const float4 wd = *reinterpret_cast<const float4*>(wq + 3 * WT_STRIDE + kb);
    // 4 rows of x
    const float4 x0 = *reinterpret_cast<const float4*>(xr0 + kb);
    const float4 x1 = *reinterpret_cast<const float4*>(xr1 + kb);
    const float4 x2 = *reinterpret_cast<const float4*>(xr2 + kb);
    const float4 x3 = *reinterpret_cast<const float4*>(xr3 + kb);

    acc0.x += x0.x*wa.x + x0.y*wa.y + x0.z*wa.z + x0.w*wa.w;
    acc0.y += x0.x*wb.x + x0.y*wb.y + x0.z*wb.z + x0.w*wb.w;
    acc0.z += x0.x*wc.x + x0.y*wc.y + x0.z*wc.z + x0.w*wc.w;
    acc0.w += x0.x*wd.x + x0.y*wd.y + x0.z*wd.z + x0.w*wd.w;

    acc1.x += x1.x*wa.x + x1.y*wa.y + x1.z*wa.z + x1.w*wa.w;
    acc1.y += x1.x*wb.x + x1.y*wb.y + x1.z*wb.z + x1.w*wb.w;
    acc1.z += x1.x*wc.x + x1.y*wc.y + x1.z*wc.z + x1.w*wc.w;
    acc1.w += x1.x*wd.x + x1.y*wd.y + x1.z*wd.z + x1.w*wd.w;

    acc2.x += x2.x*wa.x + x2.y*wa.y + x2.z*wa.z + x2.w*wa.w;
    acc2.y += x2.x*wb.x + x2.y*wb.y + x2.z*wb.z + x2.w*wb.w;
    acc2.z += x2.x*wc.x + x2.y*wc.y + x2.z*wc.z + x2.w*wc.w;
    acc2.w += x2.x*wd.x + x2.y*wd.y + x2.z*wd.z + x2.w*wd.w;

    acc3.x += x3.x*wa.x + x3.y*wa.y + x3.z*wa.z + x3.w*wa.w;
    acc3.y += x3.x*wb.x + x3.y*wb.y + x3.z*wb.z + x3.w*wb.w;
    acc3.z += x3.x*wc.x + x3.y*wc.y + x3.z*wc.z + x3.w*wc.w;
    acc3.w += x3.x*wd.x + x3.y*wd.y + x3.z*wd.z + x3.w*wd.w;
  }

  float4* xpo = reinterpret_cast<float4*>(xp + (size_t)r0 * HID + q * 4);
  const int stride4 = HID / 4;  // float4s per row
  xpo[0] = acc0;
  if (r0 + 1 < n0) xpo[1 * stride4] = acc1;
  if (r0 + 2 < n0) xpo[2 * stride4] = acc2;
  if (r0 + 3 < n0) xpo[3 * stride4] = acc3;
}

// ---------------------------------------------------------------------------
// Kernel 2: build per-target linked lists.  head[d] = last edge id, nxt[e]
// chains.  One int atomicExch per edge.  nxt is only read by LATER kernel
// launches, so the exch/write pair needs no intra-kernel ordering.
// ---------------------------------------------------------------------------
__global__ __launch_bounds__(256) void build_list(
    const int* __restrict__ dst, int E, int* head, int* __restrict__ nxt) {
  const int stride = gridDim.x * blockDim.x;
  for (int t = blockIdx.x * blockDim.x + threadIdx.x; t < E; t += stride) {
    const int d = dst[t];
    const int old = atomicExch(&head[d], t);
    nxt[t] = old;
  }
}

// ---------------------------------------------------------------------------
// Kernel 3/4: per-target list walk + mean (+ optional bias/relu).
// 4 lanes per row; lane q owns channels [4q,4q+4) as a float4 accumulator.
// All gathers are plain loads (feat is L2/L3-resident).
// ---------------------------------------------------------------------------
__global__ __launch_bounds__(256) void agg_layer(
    const float* __restrict__ feat, const int* __restrict__ srcArr,
    const int* __restrict__ head, const int* __restrict__ nxt,
    const float* __restrict__ bias, float* __restrict__ outFeat,
    int nrows, int doReluBias) {
  const int gid = blockIdx.x * blockDim.x + threadIdx.x;
  const int row = gid >> 2;
  const int q = gid & 3;
  if (row >= nrows) return;

  int e = head[row];
  float4 acc = make_float4(0.f, 0.f, 0.f, 0.f);
  int cnt = 0;
  while (e >= 0) {
    const int s = srcArr[e];
    const float4 v =
        *reinterpret_cast<const float4*>(&feat[(size_t)s * HID + q * 4]);
    acc.x += v.x; acc.y += v.y; acc.z += v.z; acc.w += v.w;
    ++cnt;
    e = nxt[e];
  }
  const float inv = 1.0f / (float)(cnt > 0 ? cnt : 1);
  float4 r;
  r.x = acc.x * inv; r.y = acc.y * inv; r.z = acc.z * inv; r.w = acc.w * inv;
  if (doReluBias) {
    const float4 b = reinterpret_cast<const float4*>(bias)[q];
    r.x = fmaxf(r.x + b.x, 0.f);
    r.y = fmaxf(r.y + b.y, 0.f);
    r.z = fmaxf(r.z + b.z, 0.f);
    r.w = fmaxf(r.w + b.w, 0.f);
  }
  *reinterpret_cast<float4*>(&outFeat[(size_t)row * HID + q * 4]) = r;
}

// ---------------------------------------------------------------------------
// Kernel 5: h2 = mean2 @ W2 + b2, then log_softmax per row.
// One 64-lane wave per output row (OUT_CH == 64 == wavefront).
// ---------------------------------------------------------------------------
__global__ __launch_bounds__(256) void out_kernel(
    const float* __restrict__ mean2, const float* __restrict__ W2,
    const float* __restrict__ b2, float* __restrict__ out, int n2) {
  const int row = blockIdx.x * 4 + (threadIdx.x >> 6);
  if (row >= n2) return;
  const int c = threadIdx.x & 63;

  float acc = b2[c];
  #pragma unroll
  for (int k = 0; k < HID; ++k) {
    acc += mean2[(size_t)row * HID + k] * W2[k * OUT_CH + c];
  }
  float mx = acc;
  #pragma unroll
  for (int off = 32; off > 0; off >>= 1) mx = fmaxf(mx, __shfl_xor(mx, off));
  float ex = expf(acc - mx);
  float sum = ex;
  #pragma unroll
  for (int off = 32; off > 0; off >>= 1) sum += __shfl_xor(sum, off);
  out[(size_t)row * OUT_CH + c] = acc - mx - logf(sum);
}

// ---------------------------------------------------------------------------
extern "C" void kernel_launch(void* const* d_in, const int* in_sizes, int n_in,
                              void* d_out, int out_size, void* d_ws, size_t ws_size,
                              hipStream_t stream) {
  const float* x   = (const float*)d_in[0];
  const float* W1  = (const float*)d_in[1];
  const float* b1  = (const float*)d_in[2];
  const float* W2  = (const float*)d_in[3];
  const float* b2  = (const float*)d_in[4];
  const int* src1  = (const int*)d_in[5];
  const int* dst1  = (const int*)d_in[6];
  const int* src2  = (const int*)d_in[7];
  const int* dst2  = (const int*)d_in[8];

  const int n0 = in_sizes[0] / IN_CH;   // 500000
  const int E1 = in_sizes[5];           // 2000000
  const int E2 = in_sizes[7];           // 400000

  // workspace layout (element offsets; all float4-aligned where needed)
  float* ws    = (float*)d_ws;
  float* xp    = ws;                                  // n0*16
  float* h1    = xp + (size_t)n0 * HID;               // N1*16
  float* mean2 = h1 + (size_t)N1_T * HID;             // N2*16
  int*   head  = (int*)(mean2 + (size_t)N2_T * HID);  // N1+N2
  int*   nxt1  = head + (N1_T + N2_T);                // E1
  int*   nxt2  = nxt1 + E1;                           // E2

  float* out = (float*)d_out;

  // head sentinel: 0xFFFFFFFF == -1
  hipMemsetAsync(head, 0xFF, (size_t)(N1_T + N2_T) * sizeof(int), stream);

  // build linked lists (layer 1 into head[0..N1), layer 2 into head[N1..))
  build_list<<<1024, 256, 0, stream>>>(dst1, E1, head, nxt1);
  build_list<<<256, 256, 0, stream>>>(dst2, E2, head + N1_T, nxt2);

  // xp = x @ W1   (256 rows per block)
  proj_kernel<<<(n0 + 255) / 256, 256, 0, stream>>>(x, W1, xp, n0);

  // layer-1: h1 = relu(mean(xp over neighbors) + b1)
  agg_layer<<<(N1_T * 4 + 255) / 256, 256, 0, stream>>>(
      xp, src1, head, nxt1, b1, h1, N1_T, 1);

  // layer-2: mean2 = mean(h1 over neighbors)
  agg_layer<<<(N2_T * 4 + 255) / 256, 256, 0, stream>>>(
      h1, src2, head + N1_T, nxt2, nullptr, mean2, N2_T, 0);

  // h2 = mean2 @ W2 + b2, log_softmax
  out_kernel<<<(N2_T + 3) / 4, 256, 0, stream>>>(mean2, W2, b2, out, N2_T);
}